// Round 1
// baseline (563.205 us; speedup 1.0000x reference)
//
#include <hip/hip_runtime.h>
#include <math.h>

#define N_ 64
#define C_ 128
#define K_ 64
#define P_ 4096
#define PT 32
#define XSTR 132   // xs2 row stride (C + 4) -> 16B-aligned rows, conflict-light
#define WSTR 132   // ws  row stride (C + 4)
#define ASTR 65    // as_ row stride (K + 1) -> conflict-free softmax/asum reads
#define TILES_PER_N 8
#define PB (P_ / TILES_PER_N)   // 512 positions per block
#define NSUB (PB / PT)          // 16 subtiles

// ---------------------------------------------------------------------------
// Main fused kernel: per (n, P-chunk): L2-normalize (folded as 1/||x||), logits
// GEMM, softmax over K, rank-32 vlad accumulation. Atomic flush to workspace.
// ---------------------------------------------------------------------------
__global__ __launch_bounds__(256, 2)
void netvlad_main(const float* __restrict__ x,
                  const float* __restrict__ conv_w,
                  const float* __restrict__ conv_b,
                  float* __restrict__ acc,
                  float* __restrict__ asum)
{
    __shared__ float xs2[PT * XSTR];   // x tile, pp-major: xs2[pp][c]
    __shared__ float ws [K_ * WSTR];   // conv_w staged: ws[k][c]
    __shared__ float as_[PT * ASTR];   // logits -> probs: as_[pp][k]
    __shared__ float rn [PT];          // 1/max(||x_col||, eps)
    __shared__ float red[8 * PT];      // reduction scratch

    const int t    = threadIdx.x;
    const int n    = blockIdx.x >> 3;
    const int tile = blockIdx.x & 7;
    const int p_base = tile * PB;

    // stage conv_w [K][C] -> ws[k][WSTR]
    for (int i = t; i < K_ * (C_ / 4); i += 256) {
        int k  = i >> 5;          // 32 float4 per row
        int c4 = i & 31;
        float4 v = ((const float4*)conv_w)[k * 32 + c4];
        *(float4*)(ws + k * WSTR + c4 * 4) = v;
    }

    // logits mapping: thread owns k in {lm, lm+16, lm+32, lm+48}, pp in {2lp, 2lp+1}
    const int lm = t & 15;
    const int lp = t >> 4;
    float cbl[4];
    #pragma unroll
    for (int i = 0; i < 4; ++i) cbl[i] = conv_b[lm + 16 * i];

    // softmax mapping: thread owns column sp, k-range sq*8..+7
    const int sp = t & 31;
    const int sq = t >> 5;

    // rank-update mapping: pg splits pp-halves, thread owns 8k x 8c
    const int pg = t >> 7;
    const int kg = (t >> 4) & 7;   // k = kg*8 + i
    const int cg = t & 15;         // c = cg + 16*j

    float facc[8][8];
    #pragma unroll
    for (int i = 0; i < 8; ++i)
        #pragma unroll
        for (int j = 0; j < 8; ++j) facc[i][j] = 0.f;
    float my_asum = 0.f;           // valid for t < 64 (k = t)

    const float* xbase = x + ((size_t)n * C_) * P_ + p_base;

    for (int sub = 0; sub < NSUB; ++sub) {
        const int p0 = sub * PT;
        __syncthreads();           // protect xs2/as_ from previous-iter readers

        // ---- load x[n][c][p0..p0+31] -> xs2[pp][c] (transposed in LDS) ----
        for (int i = t; i < C_ * (PT / 4); i += 256) {
            int c  = i >> 3;       // 8 float4 per channel row
            int pq = i & 7;
            float4 v = *(const float4*)(xbase + (size_t)c * P_ + p0 + pq * 4);
            xs2[(pq * 4 + 0) * XSTR + c] = v.x;
            xs2[(pq * 4 + 1) * XSTR + c] = v.y;
            xs2[(pq * 4 + 2) * XSTR + c] = v.z;
            xs2[(pq * 4 + 3) * XSTR + c] = v.w;
        }
        __syncthreads();

        // ---- column norms: partial over 16 channels each ----
        {
            float ss = 0.f;
            const float* row = xs2 + sp * XSTR + sq * 16;
            #pragma unroll
            for (int i = 0; i < 4; ++i) {
                float4 v = *(const float4*)(row + i * 4);
                ss += v.x * v.x + v.y * v.y + v.z * v.z + v.w * v.w;
            }
            red[sq * PT + sp] = ss;
        }
        __syncthreads();
        if (t < PT) {
            float ss = 0.f;
            #pragma unroll
            for (int q = 0; q < 8; ++q) ss += red[q * PT + t];
            rn[t] = 1.f / fmaxf(sqrtf(ss), 1e-12f);
        }
        __syncthreads();

        // ---- logits: as_[pp][k] = (w[k].x_col)*rn + b[k] ----
        {
            float lg0[4] = {0.f, 0.f, 0.f, 0.f};
            float lg1[4] = {0.f, 0.f, 0.f, 0.f};
            const float* xr0 = xs2 + (2 * lp) * XSTR;
            const float* xr1 = xr0 + XSTR;
            for (int c4 = 0; c4 < 32; ++c4) {
                float4 xa = *(const float4*)(xr0 + c4 * 4);
                float4 xb = *(const float4*)(xr1 + c4 * 4);
                #pragma unroll
                for (int i = 0; i < 4; ++i) {
                    float4 wv = *(const float4*)(ws + (lm + 16 * i) * WSTR + c4 * 4);
                    lg0[i] += wv.x * xa.x + wv.y * xa.y + wv.z * xa.z + wv.w * xa.w;
                    lg1[i] += wv.x * xb.x + wv.y * xb.y + wv.z * xb.z + wv.w * xb.w;
                }
            }
            float r0 = rn[2 * lp], r1 = rn[2 * lp + 1];
            #pragma unroll
            for (int i = 0; i < 4; ++i) {
                int k = lm + 16 * i;
                as_[(2 * lp) * ASTR + k]     = lg0[i] * r0 + cbl[i];
                as_[(2 * lp + 1) * ASTR + k] = lg1[i] * r1 + cbl[i];
            }
        }
        __syncthreads();

        // ---- softmax over K per column ----
        {
            float v[8];
            float m = -1e30f;
            #pragma unroll
            for (int i = 0; i < 8; ++i) {
                v[i] = as_[sp * ASTR + sq * 8 + i];
                m = fmaxf(m, v[i]);
            }
            red[sq * PT + sp] = m;
            __syncthreads();
            float M = red[0 * PT + sp];
            #pragma unroll
            for (int q = 1; q < 8; ++q) M = fmaxf(M, red[q * PT + sp]);
            float s = 0.f;
            #pragma unroll
            for (int i = 0; i < 8; ++i) { v[i] = expf(v[i] - M); s += v[i]; }
            __syncthreads();           // red: max-reads done before sum-writes
            red[sq * PT + sp] = s;
            __syncthreads();
            float S = 0.f;
            #pragma unroll
            for (int q = 0; q < 8; ++q) S += red[q * PT + sp];
            float inv = 1.f / S;
            #pragma unroll
            for (int i = 0; i < 8; ++i)
                as_[sp * ASTR + sq * 8 + i] = v[i] * inv;
        }
        __syncthreads();

        // ---- asum accumulation (unscaled a) ----
        if (t < K_) {
            #pragma unroll
            for (int pp = 0; pp < PT; ++pp)
                my_asum += as_[pp * ASTR + t];
        }

        // ---- rank-32 update: facc[k][c] += (a*rn)[k,pp] * x[c,pp] ----
        {
            #pragma unroll
            for (int mloc = 0; mloc < 16; ++mloc) {
                int pp = pg * 16 + mloc;
                float r = rn[pp];
                float av[8];
                #pragma unroll
                for (int i = 0; i < 8; ++i)
                    av[i] = as_[pp * ASTR + kg * 8 + i] * r;
                float xv[8];
                #pragma unroll
                for (int j = 0; j < 8; ++j)
                    xv[j] = xs2[pp * XSTR + cg + 16 * j];
                #pragma unroll
                for (int i = 0; i < 8; ++i)
                    #pragma unroll
                    for (int j = 0; j < 8; ++j)
                        facc[i][j] += av[i] * xv[j];
            }
        }
    }

    __syncthreads();
    // combine the two pg-halves in LDS (reuse ws), then one atomic per (k,c)
    if (pg == 1) {
        float* stg = ws + (t & 127) * 64;
        #pragma unroll
        for (int i = 0; i < 8; ++i)
            #pragma unroll
            for (int j = 0; j < 8; ++j)
                stg[i * 8 + j] = facc[i][j];
    }
    __syncthreads();
    if (pg == 0) {
        const float* stg = ws + t * 64;
        float* accb = acc + ((size_t)n * K_ + kg * 8) * C_;
        #pragma unroll
        for (int i = 0; i < 8; ++i)
            #pragma unroll
            for (int j = 0; j < 8; ++j)
                atomicAdd(&accb[i * C_ + cg + 16 * j], facc[i][j] + stg[i * 8 + j]);
    }
    if (t < K_) atomicAdd(&asum[n * K_ + t], my_asum);
}

// ---------------------------------------------------------------------------
// Finalize: vlad = acc - asum*centroid, intra-norm over C, global norm, store.
// One block per n; thread t owns (k = t/4, c-quarter = t%4).
// ---------------------------------------------------------------------------
__global__ __launch_bounds__(256, 4)
void netvlad_finalize(const float* __restrict__ acc,
                      const float* __restrict__ asum,
                      const float* __restrict__ centroids,
                      float* __restrict__ out)
{
    __shared__ float wred[4];
    const int t = threadIdx.x;
    const int n = blockIdx.x;
    const int k = t >> 2;
    const int part = t & 3;

    float a_k = asum[n * K_ + k];
    const float4* accv = (const float4*)(acc + ((size_t)n * K_ + k) * C_ + part * 32);
    const float4* cenv = (const float4*)(centroids + k * C_ + part * 32);
    float4 vals[8];
    float loc = 0.f;
    #pragma unroll
    for (int i = 0; i < 8; ++i) {
        float4 av = accv[i];
        float4 cv = cenv[i];
        float4 v;
        v.x = av.x - a_k * cv.x;
        v.y = av.y - a_k * cv.y;
        v.z = av.z - a_k * cv.z;
        v.w = av.w - a_k * cv.w;
        vals[i] = v;
        loc += v.x * v.x + v.y * v.y + v.z * v.z + v.w * v.w;
    }
    // reduce over the 4 threads sharing k (adjacent lanes)
    loc += __shfl_xor(loc, 1);
    loc += __shfl_xor(loc, 2);
    float rk = 1.f / fmaxf(sqrtf(loc), 1e-12f);

    float tot = 0.f;
    #pragma unroll
    for (int i = 0; i < 8; ++i) {
        float4 v = vals[i];
        v.x *= rk; v.y *= rk; v.z *= rk; v.w *= rk;
        vals[i] = v;
        tot += v.x * v.x + v.y * v.y + v.z * v.z + v.w * v.w;
    }
    #pragma unroll
    for (int o = 1; o < 64; o <<= 1) tot += __shfl_xor(tot, o);
    if ((t & 63) == 0) wred[t >> 6] = tot;
    __syncthreads();
    float T = wred[0] + wred[1] + wred[2] + wred[3];
    float rtot = 1.f / fmaxf(sqrtf(T), 1e-12f);

    float4* outv = (float4*)(out + ((size_t)n * K_ + k) * C_ + part * 32);
    #pragma unroll
    for (int i = 0; i < 8; ++i) {
        float4 v = vals[i];
        v.x *= rtot; v.y *= rtot; v.z *= rtot; v.w *= rtot;
        outv[i] = v;
    }
}

extern "C" void kernel_launch(void* const* d_in, const int* in_sizes, int n_in,
                              void* d_out, int out_size, void* d_ws, size_t ws_size,
                              hipStream_t stream)
{
    const float* x      = (const float*)d_in[0];
    // d_in[1] = xyz — unused by the reference computation
    const float* cent   = (const float*)d_in[2];
    const float* conv_w = (const float*)d_in[3];
    const float* conv_b = (const float*)d_in[4];
    float* out = (float*)d_out;

    float* acc  = (float*)d_ws;                       // [N][K][C]
    float* asum = acc + (size_t)N_ * K_ * C_;         // [N][K]
    size_t zbytes = ((size_t)N_ * K_ * C_ + (size_t)N_ * K_) * sizeof(float);
    hipMemsetAsync(d_ws, 0, zbytes, stream);

    hipLaunchKernelGGL(netvlad_main, dim3(N_ * TILES_PER_N), dim3(256), 0, stream,
                       x, conv_w, conv_b, acc, asum);
    hipLaunchKernelGGL(netvlad_finalize, dim3(N_), dim3(256), 0, stream,
                       acc, asum, cent, out);
}

// Round 2
// 527.595 us; speedup vs baseline: 1.0675x; 1.0675x over previous
//
#include <hip/hip_runtime.h>
#include <math.h>

#define N_ 64
#define C_ 128
#define K_ 64
#define P_ 4096
#define PT 64
#define XSTR 132            // x-tile row stride (132 mod 32 = 4)
#define ASTR 68             // prob-tile row stride (16B-aligned rows)
#define TILES_PER_N 8
#define PB (P_ / TILES_PER_N)   // 512
#define NSUB (PB / PT)          // 8

// row permutation for the x tile: breaks the pq*4 write pattern and the
// ppgrp+16i read pattern into <=2-way bank aliasing simultaneously
__device__ __forceinline__ int ROWP(int pp) { return pp ^ (pp >> 2); }

__global__ __launch_bounds__(256, 2)
void netvlad_main(const float* __restrict__ x,
                  const float* __restrict__ conv_w,
                  const float* __restrict__ conv_b,
                  float* __restrict__ acc_part,
                  float* __restrict__ asum_part,
                  int use_atomic)
{
    __shared__ float  xs2[PT * XSTR];   // 33792 B, x tile rows permuted by ROWP
    __shared__ float  as_[PT * ASTR];   // 17408 B, logits -> probs (rn-folded)
    __shared__ float2 redp[4 * 65];     // 2080 B, (max,sum) pairs / asum scratch
    __shared__ float  xn_[PT];          // max(||x||, eps)
    __shared__ float  rn_[PT];          // 1/xn

    const int t    = threadIdx.x;
    const int n    = blockIdx.x >> 3;
    const int tile = blockIdx.x & 7;

    // ---- staging mapping: thread owns columns pq*4..pq*4+3, channels cs+16*it
    const int pq = t & 15;
    const int cs = t >> 4;
    int wrow[4];
    #pragma unroll
    for (int j = 0; j < 4; ++j) wrow[j] = ROWP(pq * 4 + j) * XSTR;

    // ---- logits mapping: k in {kgrp+16i}, pp in {ppg+16j}
    const int kgrp = t & 15;
    const int ppg  = t >> 4;
    float cb[4];
    #pragma unroll
    for (int i = 0; i < 4; ++i) cb[i] = conv_b[kgrp + 16 * i];
    int xrow[4];
    #pragma unroll
    for (int j = 0; j < 4; ++j) xrow[j] = ROWP(ppg + 16 * j) * XSTR;

    // ---- softmax mapping: column sp, k-range sq*16..+15
    const int sp = t & 63;
    const int sq = t >> 6;

    // ---- update mapping: pp-half pg, 8 contiguous k (kg*8+), 8 contiguous c (cg*8+)
    const int pg = t >> 7;
    const int kg = (t >> 4) & 7;
    const int cg = t & 15;

    float facc[8][8];
    #pragma unroll
    for (int i = 0; i < 8; ++i)
        #pragma unroll
        for (int j = 0; j < 8; ++j) facc[i][j] = 0.f;
    float asum_acc = 0.f;

    const float* xb = x + ((size_t)n * C_) * P_ + tile * PB + pq * 4;
    const float4* wb = (const float4*)conv_w;   // w[k] = wb[k*32 .. k*32+31]

    // preload subtile 0
    float4 ld[8];
    #pragma unroll
    for (int it = 0; it < 8; ++it)
        ld[it] = *(const float4*)(xb + (size_t)(cs + 16 * it) * P_);

    for (int sub = 0; sub < NSUB; ++sub) {
        __syncthreads();   // (1) xs2/as_ free of previous-iteration readers

        // ---- stage x tile (transposed, row-permuted) + column-norm partials
        float ssq[4] = {0.f, 0.f, 0.f, 0.f};
        #pragma unroll
        for (int it = 0; it < 8; ++it) {
            float4 v = ld[it];
            int c = cs + 16 * it;
            xs2[wrow[0] + c] = v.x;
            xs2[wrow[1] + c] = v.y;
            xs2[wrow[2] + c] = v.z;
            xs2[wrow[3] + c] = v.w;
            ssq[0] += v.x * v.x;
            ssq[1] += v.y * v.y;
            ssq[2] += v.z * v.z;
            ssq[3] += v.w * v.w;
        }
        // norm partials -> as_ region, stride-17 alias (as_ is free here)
        #pragma unroll
        for (int j = 0; j < 4; ++j) as_[(pq * 4 + j) * 17 + cs] = ssq[j];
        __syncthreads();   // (2)

        // prefetch next subtile while compute runs
        if (sub + 1 < NSUB) {
            #pragma unroll
            for (int it = 0; it < 8; ++it)
                ld[it] = *(const float4*)(xb + (size_t)(cs + 16 * it) * P_ + (sub + 1) * PT);
        }

        if (t < PT) {
            float ss = 0.f;
            #pragma unroll
            for (int q = 0; q < 16; ++q) ss += as_[t * 17 + q];
            float nn = fmaxf(sqrtf(ss), 1e-12f);
            xn_[t] = nn;
            rn_[t] = 1.f / nn;
        }
        __syncthreads();   // (3)

        // ---- logits: 4k x 4pp per thread; w from global (L1-hot)
        {
            float lg[4][4];
            #pragma unroll
            for (int i = 0; i < 4; ++i)
                #pragma unroll
                for (int j = 0; j < 4; ++j) lg[i][j] = 0.f;
            for (int c4 = 0; c4 < 32; ++c4) {
                float4 xv[4];
                #pragma unroll
                for (int j = 0; j < 4; ++j)
                    xv[j] = *(const float4*)(xs2 + xrow[j] + c4 * 4);
                #pragma unroll
                for (int i = 0; i < 4; ++i) {
                    float4 wv = wb[(kgrp + 16 * i) * 32 + c4];
                    #pragma unroll
                    for (int j = 0; j < 4; ++j)
                        lg[i][j] += wv.x * xv[j].x + wv.y * xv[j].y
                                  + wv.z * xv[j].z + wv.w * xv[j].w;
                }
            }
            #pragma unroll
            for (int j = 0; j < 4; ++j) {
                int pp = ppg + 16 * j;
                float r = rn_[pp];
                #pragma unroll
                for (int i = 0; i < 4; ++i)
                    as_[pp * ASTR + kgrp + 16 * i] = lg[i][j] * r + cb[i];
            }
        }
        __syncthreads();   // (4)

        // ---- softmax over K (one cross-thread round via (m,s) pairs),
        //      writeback scaled by rn[sp]
        {
            float v[16];
            #pragma unroll
            for (int f = 0; f < 4; ++f) {
                float4 q = *(const float4*)(as_ + sp * ASTR + sq * 16 + f * 4);
                v[4 * f + 0] = q.x; v[4 * f + 1] = q.y;
                v[4 * f + 2] = q.z; v[4 * f + 3] = q.w;
            }
            float m = v[0];
            #pragma unroll
            for (int i = 1; i < 16; ++i) m = fmaxf(m, v[i]);
            float s = 0.f;
            #pragma unroll
            for (int i = 0; i < 16; ++i) { v[i] = __expf(v[i] - m); s += v[i]; }
            redp[sq * 65 + sp] = make_float2(m, s);
            __syncthreads();   // (5)
            float2 p0 = redp[0 * 65 + sp];
            float2 p1 = redp[1 * 65 + sp];
            float2 p2 = redp[2 * 65 + sp];
            float2 p3 = redp[3 * 65 + sp];
            float M = fmaxf(fmaxf(p0.x, p1.x), fmaxf(p2.x, p3.x));
            float S = p0.y * __expf(p0.x - M) + p1.y * __expf(p1.x - M)
                    + p2.y * __expf(p2.x - M) + p3.y * __expf(p3.x - M);
            float scl = __expf(m - M) * rn_[sp] / S;
            #pragma unroll
            for (int f = 0; f < 4; ++f) {
                float4 q;
                q.x = v[4 * f + 0] * scl; q.y = v[4 * f + 1] * scl;
                q.z = v[4 * f + 2] * scl; q.w = v[4 * f + 3] * scl;
                *(float4*)(as_ + sp * ASTR + sq * 16 + f * 4) = q;
            }
        }
        __syncthreads();   // (6)

        // ---- asum: sum_p a (unscaled) = sum_p as_scaled * xn
        {
            #pragma unroll
            for (int r = 0; r < 16; ++r) {
                int pp = sq * 16 + r;
                asum_acc += as_[pp * ASTR + sp] * xn_[pp];
            }
        }

        // ---- rank-64 update: facc[k][c] += as_scaled[pp][k] * x_raw[pp][c]
        {
            #pragma unroll
            for (int mloc = 0; mloc < 32; ++mloc) {
                int pp = pg * 32 + mloc;
                int row = ROWP(pp) * XSTR;
                float4 a0 = *(const float4*)(as_ + pp * ASTR + kg * 8);
                float4 a1 = *(const float4*)(as_ + pp * ASTR + kg * 8 + 4);
                float4 x0 = *(const float4*)(xs2 + row + cg * 8);
                float4 x1 = *(const float4*)(xs2 + row + cg * 8 + 4);
                float av[8] = {a0.x, a0.y, a0.z, a0.w, a1.x, a1.y, a1.z, a1.w};
                float xv[8] = {x0.x, x0.y, x0.z, x0.w, x1.x, x1.y, x1.z, x1.w};
                #pragma unroll
                for (int i = 0; i < 8; ++i)
                    #pragma unroll
                    for (int j = 0; j < 8; ++j)
                        facc[i][j] += av[i] * xv[j];
            }
        }
    }

    __syncthreads();
    // stage asum partials (redp as floats) and pg=1 facc halves (xs2, stride 66)
    {
        float* redpf = (float*)redp;
        redpf[sq * 65 + sp] = asum_acc;
    }
    if (pg == 1) {
        float* stg = xs2 + (t - 128) * 66;
        #pragma unroll
        for (int i = 0; i < 8; ++i)
            #pragma unroll
            for (int h = 0; h < 4; ++h)
                *(float2*)(stg + i * 8 + h * 2) =
                    make_float2(facc[i][2 * h], facc[i][2 * h + 1]);
    }
    __syncthreads();
    if (pg == 0) {
        const float* stg = xs2 + t * 66;
        #pragma unroll
        for (int i = 0; i < 8; ++i)
            #pragma unroll
            for (int j = 0; j < 8; ++j)
                facc[i][j] += stg[i * 8 + j];
        if (use_atomic) {
            float* dst = acc_part + ((size_t)n * K_ + kg * 8) * C_ + cg * 8;
            #pragma unroll
            for (int i = 0; i < 8; ++i)
                #pragma unroll
                for (int j = 0; j < 8; ++j)
                    atomicAdd(dst + i * C_ + j, facc[i][j]);
        } else {
            float* dst = acc_part + ((size_t)blockIdx.x * K_ + kg * 8) * C_ + cg * 8;
            #pragma unroll
            for (int i = 0; i < 8; ++i) {
                *(float4*)(dst + i * C_)     = make_float4(facc[i][0], facc[i][1],
                                                           facc[i][2], facc[i][3]);
                *(float4*)(dst + i * C_ + 4) = make_float4(facc[i][4], facc[i][5],
                                                           facc[i][6], facc[i][7]);
            }
        }
    }
    if (t < K_) {
        const float* redpf = (const float*)redp;
        float v = redpf[0 * 65 + t] + redpf[1 * 65 + t]
                + redpf[2 * 65 + t] + redpf[3 * 65 + t];
        if (use_atomic) atomicAdd(asum_part + n * K_ + t, v);
        else            asum_part[(size_t)blockIdx.x * K_ + t] = v;
    }
}

// ---------------------------------------------------------------------------
// Finalize: reduce npart slices, vlad = acc - asum*centroid, intra-norm over C,
// global norm, store. One block per n; thread t owns (k=t/4, c-quarter=t%4).
// ---------------------------------------------------------------------------
__global__ __launch_bounds__(256, 4)
void netvlad_finalize(const float* __restrict__ acc_part,
                      const float* __restrict__ asum_part,
                      const float* __restrict__ centroids,
                      float* __restrict__ out,
                      int npart)
{
    __shared__ float wred[4];
    const int t = threadIdx.x;
    const int n = blockIdx.x;
    const int k = t >> 2;
    const int part = t & 3;

    float a_k = 0.f;
    for (int s = 0; s < npart; ++s)
        a_k += asum_part[(size_t)(n * npart + s) * K_ + k];

    float4 vals[8];
    #pragma unroll
    for (int i = 0; i < 8; ++i) vals[i] = make_float4(0.f, 0.f, 0.f, 0.f);
    for (int s = 0; s < npart; ++s) {
        const float4* av = (const float4*)(acc_part
            + ((size_t)(n * npart + s) * K_ + k) * C_ + part * 32);
        #pragma unroll
        for (int i = 0; i < 8; ++i) {
            float4 a = av[i];
            vals[i].x += a.x; vals[i].y += a.y;
            vals[i].z += a.z; vals[i].w += a.w;
        }
    }

    const float4* cenv = (const float4*)(centroids + k * C_ + part * 32);
    float loc = 0.f;
    #pragma unroll
    for (int i = 0; i < 8; ++i) {
        float4 cv = cenv[i];
        float4 v = vals[i];
        v.x -= a_k * cv.x; v.y -= a_k * cv.y;
        v.z -= a_k * cv.z; v.w -= a_k * cv.w;
        vals[i] = v;
        loc += v.x * v.x + v.y * v.y + v.z * v.z + v.w * v.w;
    }
    loc += __shfl_xor(loc, 1);
    loc += __shfl_xor(loc, 2);
    float rk = 1.f / fmaxf(sqrtf(loc), 1e-12f);

    float tot = 0.f;
    #pragma unroll
    for (int i = 0; i < 8; ++i) {
        float4 v = vals[i];
        v.x *= rk; v.y *= rk; v.z *= rk; v.w *= rk;
        vals[i] = v;
        tot += v.x * v.x + v.y * v.y + v.z * v.z + v.w * v.w;
    }
    #pragma unroll
    for (int o = 1; o < 64; o <<= 1) tot += __shfl_xor(tot, o);
    if ((t & 63) == 0) wred[t >> 6] = tot;
    __syncthreads();
    float T = wred[0] + wred[1] + wred[2] + wred[3];
    float rtot = 1.f / fmaxf(sqrtf(T), 1e-12f);

    float4* outv = (float4*)(out + ((size_t)n * K_ + k) * C_ + part * 32);
    #pragma unroll
    for (int i = 0; i < 8; ++i) {
        float4 v = vals[i];
        v.x *= rtot; v.y *= rtot; v.z *= rtot; v.w *= rtot;
        outv[i] = v;
    }
}

extern "C" void kernel_launch(void* const* d_in, const int* in_sizes, int n_in,
                              void* d_out, int out_size, void* d_ws, size_t ws_size,
                              hipStream_t stream)
{
    const float* x      = (const float*)d_in[0];
    // d_in[1] = xyz — unused by the reference computation
    const float* cent   = (const float*)d_in[2];
    const float* conv_w = (const float*)d_in[3];
    const float* conv_b = (const float*)d_in[4];
    float* out = (float*)d_out;

    const int nblk = N_ * TILES_PER_N;   // 512
    size_t need = (size_t)nblk * K_ * C_ * sizeof(float)
                + (size_t)nblk * K_ * sizeof(float);
    int use_atomic = (ws_size >= need) ? 0 : 1;
    int npart = use_atomic ? 1 : TILES_PER_N;

    float* acc_part  = (float*)d_ws;
    float* asum_part = acc_part + (size_t)(use_atomic ? N_ : nblk) * K_ * C_;

    if (use_atomic) {
        size_t zbytes = ((size_t)N_ * K_ * C_ + (size_t)N_ * K_) * sizeof(float);
        hipMemsetAsync(d_ws, 0, zbytes, stream);
    }

    hipLaunchKernelGGL(netvlad_main, dim3(nblk), dim3(256), 0, stream,
                       x, conv_w, conv_b, acc_part, asum_part, use_atomic);
    hipLaunchKernelGGL(netvlad_finalize, dim3(N_), dim3(256), 0, stream,
                       acc_part, asum_part, cent, out, npart);
}

// Round 3
// 230.880 us; speedup vs baseline: 2.4394x; 2.2852x over previous
//
#include <hip/hip_runtime.h>
#include <math.h>

#define N_ 64
#define C_ 128
#define K_ 64
#define P_ 4096
#define PT 32
#define TILES_PER_N 8
#define PB (P_ / TILES_PER_N)   // 512
#define NSUB (PB / PT)          // 16
#define XH_STR 132              // xhat [p][c] row stride (u32)
#define XT_STR 36               // xT   [c][p] row stride (u32)
#define AS_STR 66               // as_  [p][k] row stride (u32)
#define RED_STR 33

typedef __attribute__((ext_vector_type(8))) short short8;
typedef __attribute__((ext_vector_type(4))) float f32x4;

union U4S8 { unsigned int u[4]; short8 s; };

// pack f32 -> (hi bf16 | lo bf16 << 16), truncation split: f ≈ hi + lo, err ≤ 2^-16 rel
__device__ __forceinline__ unsigned int pack_hl(float f) {
    unsigned int xb = __float_as_uint(f);
    float hif = __uint_as_float(xb & 0xffff0000u);
    float lo  = f - hif;
    unsigned int lob = __float_as_uint(lo) & 0xffff0000u;
    return (xb >> 16) | lob;
}

__device__ __forceinline__ void unpack8(const unsigned int p[8], short8& hi, short8& lo) {
    U4S8 h, l;
    #pragma unroll
    for (int j = 0; j < 4; ++j) {
        unsigned int a = p[2 * j], b = p[2 * j + 1];
        h.u[j] = (a & 0xffffu) | (b << 16);
        l.u[j] = (a >> 16) | (b & 0xffff0000u);
    }
    hi = h.s; lo = l.s;
}

#define MFMA16(a, b, c) __builtin_amdgcn_mfma_f32_16x16x32_bf16(a, b, c, 0, 0, 0)

__global__ __launch_bounds__(256, 3)
void netvlad_main(const float* __restrict__ x,
                  const float* __restrict__ conv_w,
                  const float* __restrict__ conv_b,
                  float* __restrict__ acc_part,
                  float* __restrict__ asum_part,
                  int use_atomic)
{
    __shared__ unsigned int xhat[PT * XH_STR];  // 16896 B: packed x, [p][c]
    __shared__ unsigned int xT  [C_ * XT_STR];  // 18432 B: packed x, [c][p]
    __shared__ unsigned int as_ [PT * AS_STR];  //  8448 B: logits f32 -> packed a
    __shared__ float        red [PT * RED_STR]; //  4224 B: ssq partials [p][cq]
    __shared__ float        rn_ [PT];           // 1/max(||x_col||,eps)

    const int t  = threadIdx.x;
    const int wv = t >> 6;          // wave 0..3
    const int l  = t & 63;          // lane
    const int n    = blockIdx.x >> 3;
    const int tile = blockIdx.x & 7;

    // ---- MFMA lane decomposition (16x16x32): m/n = lane&15, k-quad = lane>>4
    const int mrow = l & 15;
    const int kq   = l >> 4;        // 0..3

    // ---- staging mapping: thread owns c in {4cq..4cq+3}, p in {4ppq..4ppq+3}
    const int cq  = t >> 3;         // 0..31
    const int ppq = t & 7;          // 0..7

    // ---- softmax mapping: per wave, 8 columns x 8 k-segments
    const int scp   = 8 * wv + (l & 7);   // column p (0..31)
    const int skseg = l >> 3;             // k-range skseg*8..+7

    // ---- w fragments: A[m=cluster][k=c], cluster = 16*wv + mrow; resident all kernel
    short8 whi[4], wlo[4];
    {
        const float* wrow = conv_w + (size_t)(16 * wv + mrow) * C_;
        #pragma unroll
        for (int s = 0; s < 4; ++s) {
            U4S8 h, lo_;
            #pragma unroll
            for (int j = 0; j < 4; ++j) {
                float f0 = wrow[s * 32 + kq * 8 + 2 * j];
                float f1 = wrow[s * 32 + kq * 8 + 2 * j + 1];
                unsigned int b0 = __float_as_uint(f0), b1 = __float_as_uint(f1);
                float l0 = f0 - __uint_as_float(b0 & 0xffff0000u);
                float l1 = f1 - __uint_as_float(b1 & 0xffff0000u);
                unsigned int lb0 = __float_as_uint(l0) >> 16;
                unsigned int lb1 = __float_as_uint(l1) >> 16;
                h.u[j]   = (b0 >> 16) | ((b1 >> 16) << 16);
                lo_.u[j] = lb0 | (lb1 << 16);
            }
            whi[s] = h.s; wlo[s] = lo_.s;
        }
    }

    float cb8[8];
    #pragma unroll
    for (int i = 0; i < 8; ++i) cb8[i] = conv_b[skseg * 8 + i];

    f32x4 accC[8];
    #pragma unroll
    for (int nt = 0; nt < 8; ++nt) accC[nt] = (f32x4){0.f, 0.f, 0.f, 0.f};
    float asum_acc[8];
    #pragma unroll
    for (int i = 0; i < 8; ++i) asum_acc[i] = 0.f;

    const float* xbase = x + ((size_t)n * C_) * P_ + tile * PB + 4 * ppq;

    float4 ld[4];
    #pragma unroll
    for (int cc = 0; cc < 4; ++cc)
        ld[cc] = *(const float4*)(xbase + (size_t)(4 * cq + cc) * P_);

    for (int sub = 0; sub < NSUB; ++sub) {
        __syncthreads();   // (1) LDS free of previous-iteration readers

        // ---- stage packed x into both layouts + column-norm partials ----
        {
            unsigned int pk[4][4];  // [cc][j]
            float ssq[4] = {0.f, 0.f, 0.f, 0.f};
            #pragma unroll
            for (int cc = 0; cc < 4; ++cc) {
                const float* f = &ld[cc].x;
                #pragma unroll
                for (int j = 0; j < 4; ++j) {
                    pk[cc][j] = pack_hl(f[j]);
                    ssq[j] += f[j] * f[j];
                }
            }
            #pragma unroll
            for (int j = 0; j < 4; ++j) {
                uint4 v = make_uint4(pk[0][j], pk[1][j], pk[2][j], pk[3][j]);
                *(uint4*)(xhat + (4 * ppq + j) * XH_STR + 4 * cq) = v;
                red[(4 * ppq + j) * RED_STR + cq] = ssq[j];
            }
            #pragma unroll
            for (int cc = 0; cc < 4; ++cc) {
                uint4 v = make_uint4(pk[cc][0], pk[cc][1], pk[cc][2], pk[cc][3]);
                *(uint4*)(xT + (4 * cq + cc) * XT_STR + 4 * ppq) = v;
            }
        }
        // prefetch next subtile
        if (sub + 1 < NSUB) {
            #pragma unroll
            for (int cc = 0; cc < 4; ++cc)
                ld[cc] = *(const float4*)(xbase + (size_t)(4 * cq + cc) * P_ + (sub + 1) * PT);
        }
        __syncthreads();   // (2) x staged

        if (t < PT) {
            float ss = 0.f;
            #pragma unroll
            for (int q = 0; q < 32; ++q) ss += red[t * RED_STR + q];
            rn_[t] = 1.f / fmaxf(sqrtf(ss), 1e-12f);
        }

        // ---- phase A: raw dots D[cluster][p] = w · x_raw  (4-term split) ----
        #pragma unroll
        for (int j = 0; j < 2; ++j) {
            f32x4 accA = (f32x4){0.f, 0.f, 0.f, 0.f};
            const unsigned int* rowp = xhat + (j * 16 + mrow) * XH_STR + kq * 8;
            #pragma unroll
            for (int s = 0; s < 4; ++s) {
                uint4 q0 = *(const uint4*)(rowp + s * 32);
                uint4 q1 = *(const uint4*)(rowp + s * 32 + 4);
                unsigned int p8[8] = {q0.x, q0.y, q0.z, q0.w, q1.x, q1.y, q1.z, q1.w};
                short8 bhi, blo;
                unpack8(p8, bhi, blo);
                accA = MFMA16(whi[s], bhi, accA);
                accA = MFMA16(whi[s], blo, accA);
                accA = MFMA16(wlo[s], bhi, accA);
                accA = MFMA16(wlo[s], blo, accA);
            }
            #pragma unroll
            for (int r = 0; r < 4; ++r)
                as_[(j * 16 + mrow) * AS_STR + 16 * wv + kq * 4 + r] =
                    __float_as_uint(accA[r]);
        }
        __syncthreads();   // (3) logits + rn ready

        // ---- softmax over K per column (in-wave, 8 lanes/column) ----
        {
            float rnv = rn_[scp];
            float lv[8];
            #pragma unroll
            for (int i = 0; i < 8; ++i)
                lv[i] = __uint_as_float(as_[scp * AS_STR + skseg * 8 + i]) * rnv + cb8[i];
            float m = lv[0];
            #pragma unroll
            for (int i = 1; i < 8; ++i) m = fmaxf(m, lv[i]);
            float s = 0.f;
            #pragma unroll
            for (int i = 0; i < 8; ++i) s += __expf(lv[i] - m);
            #pragma unroll
            for (int off = 8; off <= 32; off <<= 1) {
                float mo = __shfl_xor(m, off);
                float so = __shfl_xor(s, off);
                float Mn = fmaxf(m, mo);
                s = s * __expf(m - Mn) + so * __expf(mo - Mn);
                m = Mn;
            }
            float inv = 1.f / s;
            #pragma unroll
            for (int i = 0; i < 8; ++i) {
                float a = __expf(lv[i] - m) * inv;
                asum_acc[i] += a;
                as_[scp * AS_STR + skseg * 8 + i] = pack_hl(a * rnv);
            }
        }
        __syncthreads();   // (4) packed a ready

        // ---- phase C: accC[cluster][c] += a_scaled · x_raw (4-term split) ----
        {
            unsigned int pa[8];
            #pragma unroll
            for (int i = 0; i < 8; ++i)
                pa[i] = as_[(kq * 8 + i) * AS_STR + 16 * wv + mrow];
            short8 ahi, alo;
            unpack8(pa, ahi, alo);
            #pragma unroll
            for (int nt = 0; nt < 8; ++nt) {
                const unsigned int* rp = xT + (nt * 16 + mrow) * XT_STR + kq * 8;
                uint4 q0 = *(const uint4*)(rp);
                uint4 q1 = *(const uint4*)(rp + 4);
                unsigned int p8[8] = {q0.x, q0.y, q0.z, q0.w, q1.x, q1.y, q1.z, q1.w};
                short8 xhi, xlo;
                unpack8(p8, xhi, xlo);
                accC[nt] = MFMA16(ahi, xhi, accC[nt]);
                accC[nt] = MFMA16(ahi, xlo, accC[nt]);
                accC[nt] = MFMA16(alo, xhi, accC[nt]);
                accC[nt] = MFMA16(alo, xlo, accC[nt]);
            }
        }
    }

    __syncthreads();
    // ---- asum: in-wave reduce over the 8 columns, stage per-wave, combine ----
    {
        #pragma unroll
        for (int i = 0; i < 8; ++i) {
            asum_acc[i] += __shfl_xor(asum_acc[i], 1);
            asum_acc[i] += __shfl_xor(asum_acc[i], 2);
            asum_acc[i] += __shfl_xor(asum_acc[i], 4);
        }
        float* fred = (float*)xhat;    // reuse
        if ((l & 7) == 0) {
            #pragma unroll
            for (int i = 0; i < 8; ++i)
                fred[wv * 64 + skseg * 8 + i] = asum_acc[i];
        }
    }
    // ---- flush accC ----
    if (!use_atomic) {
        float* dst = acc_part + ((size_t)blockIdx.x * K_ + 16 * wv + kq * 4) * C_ + mrow;
        #pragma unroll
        for (int r = 0; r < 4; ++r)
            #pragma unroll
            for (int nt = 0; nt < 8; ++nt)
                dst[r * C_ + nt * 16] = accC[nt][r];
    } else {
        float* dst = acc_part + ((size_t)n * K_ + 16 * wv + kq * 4) * C_ + mrow;
        #pragma unroll
        for (int r = 0; r < 4; ++r)
            #pragma unroll
            for (int nt = 0; nt < 8; ++nt)
                atomicAdd(dst + r * C_ + nt * 16, accC[nt][r]);
    }
    __syncthreads();
    if (t < K_) {
        const float* fred = (const float*)xhat;
        float v = fred[0 * 64 + t] + fred[1 * 64 + t] + fred[2 * 64 + t] + fred[3 * 64 + t];
        if (use_atomic) atomicAdd(asum_part + n * K_ + t, v);
        else            asum_part[(size_t)blockIdx.x * K_ + t] = v;
    }
}

// ---------------------------------------------------------------------------
// Finalize: reduce npart slices, vlad = acc - asum*centroid, intra-norm over C,
// global norm, store. One block per n; thread t owns (k=t/4, c-quarter=t%4).
// ---------------------------------------------------------------------------
__global__ __launch_bounds__(256, 4)
void netvlad_finalize(const float* __restrict__ acc_part,
                      const float* __restrict__ asum_part,
                      const float* __restrict__ centroids,
                      float* __restrict__ out,
                      int npart)
{
    __shared__ float wred[4];
    const int t = threadIdx.x;
    const int n = blockIdx.x;
    const int k = t >> 2;
    const int part = t & 3;

    float a_k = 0.f;
    for (int s = 0; s < npart; ++s)
        a_k += asum_part[(size_t)(n * npart + s) * K_ + k];

    float4 vals[8];
    #pragma unroll
    for (int i = 0; i < 8; ++i) vals[i] = make_float4(0.f, 0.f, 0.f, 0.f);
    for (int s = 0; s < npart; ++s) {
        const float4* av = (const float4*)(acc_part
            + ((size_t)(n * npart + s) * K_ + k) * C_ + part * 32);
        #pragma unroll
        for (int i = 0; i < 8; ++i) {
            float4 a = av[i];
            vals[i].x += a.x; vals[i].y += a.y;
            vals[i].z += a.z; vals[i].w += a.w;
        }
    }

    const float4* cenv = (const float4*)(centroids + k * C_ + part * 32);
    float loc = 0.f;
    #pragma unroll
    for (int i = 0; i < 8; ++i) {
        float4 cv = cenv[i];
        float4 v = vals[i];
        v.x -= a_k * cv.x; v.y -= a_k * cv.y;
        v.z -= a_k * cv.z; v.w -= a_k * cv.w;
        vals[i] = v;
        loc += v.x * v.x + v.y * v.y + v.z * v.z + v.w * v.w;
    }
    loc += __shfl_xor(loc, 1);
    loc += __shfl_xor(loc, 2);
    float rk = 1.f / fmaxf(sqrtf(loc), 1e-12f);

    float tot = 0.f;
    #pragma unroll
    for (int i = 0; i < 8; ++i) {
        float4 v = vals[i];
        v.x *= rk; v.y *= rk; v.z *= rk; v.w *= rk;
        vals[i] = v;
        tot += v.x * v.x + v.y * v.y + v.z * v.z + v.w * v.w;
    }
    #pragma unroll
    for (int o = 1; o < 64; o <<= 1) tot += __shfl_xor(tot, o);
    if ((t & 63) == 0) wred[t >> 6] = tot;
    __syncthreads();
    float T = wred[0] + wred[1] + wred[2] + wred[3];
    float rtot = 1.f / fmaxf(sqrtf(T), 1e-12f);

    float4* outv = (float4*)(out + ((size_t)n * K_ + k) * C_ + part * 32);
    #pragma unroll
    for (int i = 0; i < 8; ++i) {
        float4 v = vals[i];
        v.x *= rtot; v.y *= rtot; v.z *= rtot; v.w *= rtot;
        outv[i] = v;
    }
}

extern "C" void kernel_launch(void* const* d_in, const int* in_sizes, int n_in,
                              void* d_out, int out_size, void* d_ws, size_t ws_size,
                              hipStream_t stream)
{
    const float* x      = (const float*)d_in[0];
    // d_in[1] = xyz — unused by the reference computation
    const float* cent   = (const float*)d_in[2];
    const float* conv_w = (const float*)d_in[3];
    const float* conv_b = (const float*)d_in[4];
    float* out = (float*)d_out;

    const int nblk = N_ * TILES_PER_N;   // 512
    size_t need = (size_t)nblk * K_ * C_ * sizeof(float)
                + (size_t)nblk * K_ * sizeof(float);
    int use_atomic = (ws_size >= need) ? 0 : 1;
    int npart = use_atomic ? 1 : TILES_PER_N;

    float* acc_part  = (float*)d_ws;
    float* asum_part = acc_part + (size_t)(use_atomic ? N_ : nblk) * K_ * C_;

    if (use_atomic) {
        size_t zbytes = ((size_t)N_ * K_ * C_ + (size_t)N_ * K_) * sizeof(float);
        hipMemsetAsync(d_ws, 0, zbytes, stream);
    }

    hipLaunchKernelGGL(netvlad_main, dim3(nblk), dim3(256), 0, stream,
                       x, conv_w, conv_b, acc_part, asum_part, use_atomic);
    hipLaunchKernelGGL(netvlad_finalize, dim3(N_), dim3(256), 0, stream,
                       acc_part, asum_part, cent, out, npart);
}

// Round 4
// 222.127 us; speedup vs baseline: 2.5355x; 1.0394x over previous
//
#include <hip/hip_runtime.h>
#include <math.h>

#define N_ 64
#define C_ 128
#define K_ 64
#define P_ 4096
#define PT 32
#define TILES_PER_N 8
#define PB (P_ / TILES_PER_N)   // 512
#define NSUB (PB / PT)          // 16

typedef __attribute__((ext_vector_type(8))) short short8;
typedef __attribute__((ext_vector_type(4))) float f32x4;

union U4S8 { uint4 u4; unsigned int u[4]; short8 s; };

// (hi bf16 of a) in low16, (hi bf16 of b) in high16 — MFMA k-pair order
__device__ __forceinline__ unsigned int pair_hi(float a, float b) {
    return (__float_as_uint(b) & 0xffff0000u) | (__float_as_uint(a) >> 16);
}
__device__ __forceinline__ float lo_part(float f) {
    return f - __uint_as_float(__float_as_uint(f) & 0xffff0000u);
}

#define MFMA16(a, b, c) __builtin_amdgcn_mfma_f32_16x16x32_bf16(a, b, c, 0, 0, 0)

// swizzle mask for the x [p][c] planes: bijective over consecutive-p octets
// (phase-A reads) AND over stride-4 p sets (staging writes)
__device__ __forceinline__ int pmask(int p) { return (p & 7) ^ ((p >> 3) & 3); }

__global__ __launch_bounds__(256, 2)
void netvlad_main(const float* __restrict__ x,
                  const float* __restrict__ conv_w,
                  const float* __restrict__ conv_b,
                  float* __restrict__ acc_part,
                  float* __restrict__ asum_part,
                  int use_atomic)
{
    // all planes store bf16-PAIRS (u32) in MFMA operand order
    __shared__ unsigned int xhi [PT * 64];   // 8 KB  [p][c-pair], chunk-XOR pmask(p)
    __shared__ unsigned int xlo [PT * 64];   // 8 KB
    __shared__ unsigned int xthi[C_ * 20];   // 10 KB [c][p-pair], stride 20
    __shared__ unsigned int xtlo[C_ * 20];   // 10 KB
    __shared__ unsigned int ahi_[K_ * 20];   // 5 KB  [k][p-pair], stride 20, chunk-XOR (k>>3)&3
    __shared__ unsigned int alo_[K_ * 20];   // 5 KB
    __shared__ float        asl [PT * 68];   // 8.5 KB raw logits f32 [p][k]
    __shared__ float        red2[4 * 33];    // per-wave ssq partials
    __shared__ float        rn_ [PT];

    const int t  = threadIdx.x;
    const int wv = t >> 6;
    const int l  = t & 63;
    const int n    = blockIdx.x >> 3;
    const int tile = blockIdx.x & 7;

    const int mrow = l & 15;     // MFMA m/n lane index
    const int kq   = l >> 4;     // MFMA k-quad

    // staging: thread owns c in {4cq..4cq+3}, p in {4ppq..4ppq+3}
    const int ppq = t & 7;
    const int cq  = t >> 3;      // 0..31

    // softmax: column scol, k-range kseg*8..+7
    const int kseg = l >> 3;
    const int scol = 8 * wv + (l & 7);

    // phase A: wave -> n-tile ntp (p half), m-tiles {mt0, mt0+1}
    const int ntp = wv & 1;
    const int mt0 = 2 * (wv >> 1);

    // ---- conv_w fragments resident in registers for the wave's two m-tiles ----
    short8 whi[2][4], wlo[2][4];
    #pragma unroll
    for (int mtl = 0; mtl < 2; ++mtl) {
        const float* wr = conv_w + (size_t)((mt0 + mtl) * 16 + mrow) * C_;
        #pragma unroll
        for (int s = 0; s < 4; ++s) {
            U4S8 h, lo;
            #pragma unroll
            for (int j = 0; j < 4; ++j) {
                float f0 = wr[s * 32 + kq * 8 + 2 * j];
                float f1 = wr[s * 32 + kq * 8 + 2 * j + 1];
                h.u[j]  = pair_hi(f0, f1);
                lo.u[j] = pair_hi(lo_part(f0), lo_part(f1));
            }
            whi[mtl][s] = h.s; wlo[mtl][s] = lo.s;
        }
    }
    float cb8[8];
    #pragma unroll
    for (int i = 0; i < 8; ++i) cb8[i] = conv_b[kseg * 8 + i];

    f32x4 accC[4][2];
    #pragma unroll
    for (int mt = 0; mt < 4; ++mt)
        #pragma unroll
        for (int ntl = 0; ntl < 2; ++ntl) accC[mt][ntl] = (f32x4){0.f, 0.f, 0.f, 0.f};
    float asum_acc[8];
    #pragma unroll
    for (int i = 0; i < 8; ++i) asum_acc[i] = 0.f;

    const float* xb = x + ((size_t)n * C_) * P_ + tile * PB + 4 * ppq;

    float4 ld[4];
    #pragma unroll
    for (int cc = 0; cc < 4; ++cc)
        ld[cc] = *(const float4*)(xb + (size_t)(4 * cq + cc) * P_);

    for (int sub = 0; sub < NSUB; ++sub) {
        __syncthreads();   // (1) LDS free of previous-iteration readers

        // ---- stage both layouts (hi/lo planes) + column-norm partials ----
        {
            const float* lf = (const float*)ld;   // lf[cc*4+j]
            // xT planes: rows c, p-pairs
            #pragma unroll
            for (int cc = 0; cc < 4; ++cc) {
                float4 v = ld[cc];
                int c = 4 * cq + cc;
                uint2 wh; wh.x = pair_hi(v.x, v.y); wh.y = pair_hi(v.z, v.w);
                *(uint2*)(xthi + c * 20 + 2 * ppq) = wh;
                uint2 wl; wl.x = pair_hi(lo_part(v.x), lo_part(v.y));
                wl.y = pair_hi(lo_part(v.z), lo_part(v.w));
                *(uint2*)(xtlo + c * 20 + 2 * ppq) = wl;
            }
            // x planes: rows p (swizzled chunks), c-pairs
            float ssq[4];
            #pragma unroll
            for (int j = 0; j < 4; ++j) {
                int p = 4 * ppq + j;
                int ch = cq >> 1;
                int chp = (ch & 8) | ((ch ^ pmask(p)) & 7);
                int base = p * 64 + (chp << 2) + ((cq & 1) << 1);
                float f0 = lf[0 * 4 + j], f1 = lf[1 * 4 + j];
                float f2 = lf[2 * 4 + j], f3 = lf[3 * 4 + j];
                uint2 wh; wh.x = pair_hi(f0, f1); wh.y = pair_hi(f2, f3);
                *(uint2*)(xhi + base) = wh;
                uint2 wl; wl.x = pair_hi(lo_part(f0), lo_part(f1));
                wl.y = pair_hi(lo_part(f2), lo_part(f3));
                *(uint2*)(xlo + base) = wl;
                ssq[j] = f0 * f0 + f1 * f1 + f2 * f2 + f3 * f3;
            }
            #pragma unroll
            for (int j = 0; j < 4; ++j) {
                ssq[j] += __shfl_xor(ssq[j], 8);
                ssq[j] += __shfl_xor(ssq[j], 16);
                ssq[j] += __shfl_xor(ssq[j], 32);
            }
            if (l < 8) {
                #pragma unroll
                for (int j = 0; j < 4; ++j) red2[wv * 33 + 4 * l + j] = ssq[j];
            }
        }
        // prefetch next subtile
        if (sub + 1 < NSUB) {
            #pragma unroll
            for (int cc = 0; cc < 4; ++cc)
                ld[cc] = *(const float4*)(xb + (size_t)(4 * cq + cc) * P_ + (sub + 1) * PT);
        }
        __syncthreads();   // (2) staged

        if (t < PT) {
            float ss = red2[t] + red2[33 + t] + red2[66 + t] + red2[99 + t];
            rn_[t] = 1.f / fmaxf(sqrtf(ss), 1e-12f);
        }

        // ---- phase A: raw logits D[k][p] = w·x (3-term split), B-frag shared ----
        {
            const int prow = ntp * 16 + mrow;
            const int msk = pmask(prow);
            f32x4 a0 = (f32x4){0.f, 0.f, 0.f, 0.f};
            f32x4 a1 = (f32x4){0.f, 0.f, 0.f, 0.f};
            #pragma unroll
            for (int s = 0; s < 4; ++s) {
                int ch = s * 4 + kq;
                int chp = (ch & 8) | ((ch ^ msk) & 7);
                int idx = prow * 64 + (chp << 2);
                U4S8 bh, bl;
                bh.u4 = *(const uint4*)(xhi + idx);
                bl.u4 = *(const uint4*)(xlo + idx);
                a0 = MFMA16(whi[0][s], bh.s, a0);
                a0 = MFMA16(whi[0][s], bl.s, a0);
                a0 = MFMA16(wlo[0][s], bh.s, a0);
                a1 = MFMA16(whi[1][s], bh.s, a1);
                a1 = MFMA16(whi[1][s], bl.s, a1);
                a1 = MFMA16(wlo[1][s], bh.s, a1);
            }
            *(f32x4*)(asl + prow * 68 + (mt0    ) * 16 + kq * 4) = a0;
            *(f32x4*)(asl + prow * 68 + (mt0 + 1) * 16 + kq * 4) = a1;
        }
        __syncthreads();   // (3) logits + rn ready

        // ---- softmax over K per column (in-wave) + write packed a·rn ----
        {
            float rnv = rn_[scol];
            f32x4 q0 = *(const f32x4*)(asl + scol * 68 + kseg * 8);
            f32x4 q1 = *(const f32x4*)(asl + scol * 68 + kseg * 8 + 4);
            float lv[8];
            #pragma unroll
            for (int i = 0; i < 4; ++i) { lv[i] = q0[i] * rnv + cb8[i]; }
            #pragma unroll
            for (int i = 0; i < 4; ++i) { lv[4 + i] = q1[i] * rnv + cb8[4 + i]; }
            float m = lv[0];
            #pragma unroll
            for (int i = 1; i < 8; ++i) m = fmaxf(m, lv[i]);
            float s = 0.f;
            #pragma unroll
            for (int i = 0; i < 8; ++i) s += __expf(lv[i] - m);
            #pragma unroll
            for (int off = 8; off <= 32; off <<= 1) {
                float mo = __shfl_xor(m, off);
                float so = __shfl_xor(s, off);
                float Mn = fmaxf(m, mo);
                s = s * __expf(m - Mn) + so * __expf(mo - Mn);
                m = Mn;
            }
            float inv = 1.f / s;
            const int p2 = scol >> 1;
            #pragma unroll
            for (int i = 0; i < 8; ++i) {
                float a = __expf(lv[i] - m) * inv;
                asum_acc[i] += a;
                float av = a * rnv;
                float pav = __shfl_xor(av, 1);
                if ((l & 1) == 0) {
                    int k = kseg * 8 + i;
                    int chp = wv ^ (kseg & 3);
                    int off = k * 20 + (chp << 2) + (p2 & 3);
                    ahi_[off] = pair_hi(av, pav);
                    alo_[off] = pair_hi(lo_part(av), lo_part(pav));
                }
            }
        }
        __syncthreads();   // (4) packed a ready

        // ---- phase C: accC[k][c] += a_scaled · x (3-term split) ----
        {
            U4S8 ah[4], al[4];
            #pragma unroll
            for (int mt = 0; mt < 4; ++mt) {
                int ar = mt * 16 + mrow;
                int chp = kq ^ ((ar >> 3) & 3);
                int idx = ar * 20 + (chp << 2);
                ah[mt].u4 = *(const uint4*)(ahi_ + idx);
                al[mt].u4 = *(const uint4*)(alo_ + idx);
            }
            #pragma unroll
            for (int ntl = 0; ntl < 2; ++ntl) {
                int cr = (2 * wv + ntl) * 16 + mrow;
                int xi = cr * 20 + kq * 4;
                U4S8 xh, xl2;
                xh.u4  = *(const uint4*)(xthi + xi);
                xl2.u4 = *(const uint4*)(xtlo + xi);
                #pragma unroll
                for (int mt = 0; mt < 4; ++mt) {
                    accC[mt][ntl] = MFMA16(ah[mt].s, xh.s,  accC[mt][ntl]);
                    accC[mt][ntl] = MFMA16(ah[mt].s, xl2.s, accC[mt][ntl]);
                    accC[mt][ntl] = MFMA16(al[mt].s, xh.s,  accC[mt][ntl]);
                }
            }
        }
    }

    __syncthreads();
    // ---- asum: reduce over the wave's 8 columns, stage, combine ----
    #pragma unroll
    for (int i = 0; i < 8; ++i) {
        asum_acc[i] += __shfl_xor(asum_acc[i], 1);
        asum_acc[i] += __shfl_xor(asum_acc[i], 2);
        asum_acc[i] += __shfl_xor(asum_acc[i], 4);
    }
    float* fred = (float*)xhi;   // reuse
    if ((l & 7) == 0) {
        #pragma unroll
        for (int i = 0; i < 8; ++i) fred[wv * 64 + kseg * 8 + i] = asum_acc[i];
    }
    // ---- flush accC (D layout: m = mt*16+kq*4+r, n = (2wv+ntl)*16+mrow) ----
    if (!use_atomic) {
        float* dst = acc_part + (size_t)blockIdx.x * K_ * C_;
        #pragma unroll
        for (int mt = 0; mt < 4; ++mt)
            #pragma unroll
            for (int r = 0; r < 4; ++r)
                #pragma unroll
                for (int ntl = 0; ntl < 2; ++ntl)
                    dst[(mt * 16 + kq * 4 + r) * C_ + (2 * wv + ntl) * 16 + mrow] =
                        accC[mt][ntl][r];
    } else {
        float* dst = acc_part + (size_t)n * K_ * C_;
        #pragma unroll
        for (int mt = 0; mt < 4; ++mt)
            #pragma unroll
            for (int r = 0; r < 4; ++r)
                #pragma unroll
                for (int ntl = 0; ntl < 2; ++ntl)
                    atomicAdd(dst + (mt * 16 + kq * 4 + r) * C_ + (2 * wv + ntl) * 16 + mrow,
                              accC[mt][ntl][r]);
    }
    __syncthreads();
    if (t < K_) {
        float v = fred[t] + fred[64 + t] + fred[128 + t] + fred[192 + t];
        if (use_atomic) atomicAdd(asum_part + n * K_ + t, v);
        else            asum_part[(size_t)blockIdx.x * K_ + t] = v;
    }
}

// ---------------------------------------------------------------------------
// Finalize: reduce npart slices, vlad = acc - asum*centroid, intra-norm over C,
// global norm, store. One block per n; thread t owns (k=t/4, c-quarter=t%4).
// ---------------------------------------------------------------------------
__global__ __launch_bounds__(256, 4)
void netvlad_finalize(const float* __restrict__ acc_part,
                      const float* __restrict__ asum_part,
                      const float* __restrict__ centroids,
                      float* __restrict__ out,
                      int npart)
{
    __shared__ float wred[4];
    const int t = threadIdx.x;
    const int n = blockIdx.x;
    const int k = t >> 2;
    const int part = t & 3;

    float a_k = 0.f;
    for (int s = 0; s < npart; ++s)
        a_k += asum_part[(size_t)(n * npart + s) * K_ + k];

    float4 vals[8];
    #pragma unroll
    for (int i = 0; i < 8; ++i) vals[i] = make_float4(0.f, 0.f, 0.f, 0.f);
    for (int s = 0; s < npart; ++s) {
        const float4* av = (const float4*)(acc_part
            + ((size_t)(n * npart + s) * K_ + k) * C_ + part * 32);
        #pragma unroll
        for (int i = 0; i < 8; ++i) {
            float4 a = av[i];
            vals[i].x += a.x; vals[i].y += a.y;
            vals[i].z += a.z; vals[i].w += a.w;
        }
    }

    const float4* cenv = (const float4*)(centroids + k * C_ + part * 32);
    float loc = 0.f;
    #pragma unroll
    for (int i = 0; i < 8; ++i) {
        float4 cv = cenv[i];
        float4 v = vals[i];
        v.x -= a_k * cv.x; v.y -= a_k * cv.y;
        v.z -= a_k * cv.z; v.w -= a_k * cv.w;
        vals[i] = v;
        loc += v.x * v.x + v.y * v.y + v.z * v.z + v.w * v.w;
    }
    loc += __shfl_xor(loc, 1);
    loc += __shfl_xor(loc, 2);
    float rk = 1.f / fmaxf(sqrtf(loc), 1e-12f);

    float tot = 0.f;
    #pragma unroll
    for (int i = 0; i < 8; ++i) {
        float4 v = vals[i];
        v.x *= rk; v.y *= rk; v.z *= rk; v.w *= rk;
        vals[i] = v;
        tot += v.x * v.x + v.y * v.y + v.z * v.z + v.w * v.w;
    }
    #pragma unroll
    for (int o = 1; o < 64; o <<= 1) tot += __shfl_xor(tot, o);
    if ((t & 63) == 0) wred[t >> 6] = tot;
    __syncthreads();
    float T = wred[0] + wred[1] + wred[2] + wred[3];
    float rtot = 1.f / fmaxf(sqrtf(T), 1e-12f);

    float4* outv = (float4*)(out + ((size_t)n * K_ + k) * C_ + part * 32);
    #pragma unroll
    for (int i = 0; i < 8; ++i) {
        float4 v = vals[i];
        v.x *= rtot; v.y *= rtot; v.z *= rtot; v.w *= rtot;
        outv[i] = v;
    }
}

extern "C" void kernel_launch(void* const* d_in, const int* in_sizes, int n_in,
                              void* d_out, int out_size, void* d_ws, size_t ws_size,
                              hipStream_t stream)
{
    const float* x      = (const float*)d_in[0];
    // d_in[1] = xyz — unused by the reference computation
    const float* cent   = (const float*)d_in[2];
    const float* conv_w = (const float*)d_in[3];
    const float* conv_b = (const float*)d_in[4];
    float* out = (float*)d_out;

    const int nblk = N_ * TILES_PER_N;   // 512
    size_t need = (size_t)nblk * K_ * C_ * sizeof(float)
                + (size_t)nblk * K_ * sizeof(float);
    int use_atomic = (ws_size >= need) ? 0 : 1;
    int npart = use_atomic ? 1 : TILES_PER_N;

    float* acc_part  = (float*)d_ws;
    float* asum_part = acc_part + (size_t)(use_atomic ? N_ : nblk) * K_ * C_;

    if (use_atomic) {
        size_t zbytes = ((size_t)N_ * K_ * C_ + (size_t)N_ * K_) * sizeof(float);
        hipMemsetAsync(d_ws, 0, zbytes, stream);
    }

    hipLaunchKernelGGL(netvlad_main, dim3(nblk), dim3(256), 0, stream,
                       x, conv_w, conv_b, acc_part, asum_part, use_atomic);
    hipLaunchKernelGGL(netvlad_finalize, dim3(N_), dim3(256), 0, stream,
                       acc_part, asum_part, cent, out, npart);
}